// Round 9
// baseline (528.108 us; speedup 1.0000x reference)
//
#include <hip/hip_runtime.h>
#include <hip/hip_bf16.h>
#include <math.h>

#define NEG_ATT 0.2f
#define NEG_ACT 0.01f
#define NEG_BIG -1e30f
#define NRANGE 8   // dst-space ranges, mapped to XCDs via blockIdx%8

typedef __hip_bfloat16  bf16;

__device__ __forceinline__ float bflo(unsigned w) { return __uint_as_float(w << 16); }
__device__ __forceinline__ float bfhi(unsigned w) { return __uint_as_float(w & 0xFFFF0000u); }

// ============================ CSR build ============================
__global__ void k_zero(int* __restrict__ counts, int N) {
    int i = blockIdx.x * blockDim.x + threadIdx.x;
    if (i < N) counts[i] = 0;
}

__global__ void k_count(const int* __restrict__ ei, int E, int N, int* __restrict__ counts) {
    const int r = blockIdx.x & (NRANGE - 1);
    const int e = (blockIdx.x >> 3) * blockDim.x + threadIdx.x;
    if (e >= E + N) return;
    const int dlo = (int)(((long)r * N) / NRANGE);
    const int dhi = (int)(((long)(r + 1) * N) / NRANGE);
    int d = (e < E) ? ei[E + e] : e - E;
    if (d < dlo || d >= dhi) return;
    atomicAdd(&counts[d], 1);
}

__global__ void k_scan1(const int* __restrict__ counts, int N, int* __restrict__ bsum) {
    const int i = blockIdx.x * 256 + threadIdx.x;
    int v = (i < N) ? counts[i] : 0;
    #pragma unroll
    for (int off = 32; off >= 1; off >>= 1) v += __shfl_xor(v, off);
    __shared__ int ws[4];
    if ((threadIdx.x & 63) == 0) ws[threadIdx.x >> 6] = v;
    __syncthreads();
    if (threadIdx.x == 0) bsum[blockIdx.x] = ws[0] + ws[1] + ws[2] + ws[3];
}

__global__ void k_scan2(int* __restrict__ bsum, int NB, int* __restrict__ rowptrN) {
    __shared__ int ps[256];
    const int t = threadIdx.x;
    int v = (t < NB) ? bsum[t] : 0;
    ps[t] = v;
    __syncthreads();
    for (int off = 1; off < 256; off <<= 1) {
        int u = (t >= off) ? ps[t - off] : 0;
        __syncthreads();
        ps[t] += u;
        __syncthreads();
    }
    if (t < NB) bsum[t] = ps[t] - v;          // exclusive
    if (t == 255) *rowptrN = ps[255];         // total
}

__global__ void k_scan3(const int* __restrict__ counts, int N, const int* __restrict__ bsum,
                        int* __restrict__ rowptr, int* __restrict__ cursor) {
    __shared__ int ps[256];
    const int t = threadIdx.x;
    const int i = blockIdx.x * 256 + t;
    int v = (i < N) ? counts[i] : 0;
    ps[t] = v;
    __syncthreads();
    for (int off = 1; off < 256; off <<= 1) {
        int u = (t >= off) ? ps[t - off] : 0;
        __syncthreads();
        ps[t] += u;
        __syncthreads();
    }
    if (i < N) {
        int ex = ps[t] - v + bsum[blockIdx.x];
        rowptr[i] = ex;
        cursor[i] = ex;
    }
}

__global__ void k_scatter(const int* __restrict__ ei, int E, int N,
                          int* __restrict__ cursor, int* __restrict__ col) {
    const int r = blockIdx.x & (NRANGE - 1);
    const int e = (blockIdx.x >> 3) * blockDim.x + threadIdx.x;
    if (e >= E + N) return;
    const int dlo = (int)(((long)r * N) / NRANGE);
    const int dhi = (int)(((long)(r + 1) * N) / NRANGE);
    int d = (e < E) ? ei[E + e] : e - E;
    if (d < dlo || d >= dhi) return;
    int s = (e < E) ? ei[e] : d;
    int pos = atomicAdd(&cursor[d], 1);
    col[pos] = s;
}

// ============================ GEMM1 fused with att1: h1b = bf16(x@W1), a1s/a1d ============================
__global__ void k_gemm1(const float* __restrict__ x, const float* __restrict__ W1,
                        const float* __restrict__ a1sw, const float* __restrict__ a1dw,
                        bf16* __restrict__ h1b, float* __restrict__ a1s, float* __restrict__ a1d,
                        int N) {
    __shared__ float xs[8][128];
    const int j = threadIdx.x;
    const int row0 = blockIdx.x * 8;
    #pragma unroll
    for (int r = 0; r < 8; ++r) {
        int n = row0 + r;
        xs[r][j] = (n < N) ? x[(long)n * 128 + j] : 0.f;
    }
    __syncthreads();
    float acc[8];
    #pragma unroll
    for (int r = 0; r < 8; ++r) acc[r] = 0.f;
    for (int k = 0; k < 128; ++k) {
        float w = W1[k * 128 + j];
        #pragma unroll
        for (int r = 0; r < 8; ++r) acc[r] = fmaf(xs[r][k], w, acc[r]);
    }
    const float asw = a1sw[j], adw = a1dw[j];
    #pragma unroll
    for (int r = 0; r < 8; ++r) {
        int n = row0 + r;
        float vs = acc[r] * asw, vd = acc[r] * adw;
        #pragma unroll
        for (int m = 16; m >= 1; m >>= 1) {
            vs += __shfl_xor(vs, m, 32);
            vd += __shfl_xor(vd, m, 32);
        }
        if (n < N) {
            h1b[(long)n * 128 + j] = __float2bfloat16(acc[r]);
            if ((j & 31) == 0) { a1s[n * 4 + (j >> 5)] = vs; a1d[n * 4 + (j >> 5)] = vd; }
        }
    }
}

// ============================ layer-1 fused softmax+aggregate ============================
// phase 2: full wave per edge; s is wave-uniform via readfirstlane -> SGPR row base,
// loop-invariant lane*4 voffset. Lane owns channels {2*lane, 2*lane+1}.
__global__ void k_aggr1(const int* __restrict__ rowptr, const int* __restrict__ col,
                        const unsigned* __restrict__ h1q, const float* __restrict__ a1s,
                        const float* __restrict__ a1d, const float* __restrict__ b1,
                        float* __restrict__ g1, int N) {
    __shared__ float als[4][64][4];
    __shared__ int   scol[4][64];
    const int w = threadIdx.x >> 6;
    const int lane = threadIdx.x & 63;
    const int d = blockIdx.x * 4 + w;
    if (d >= N) return;
    const int lo = rowptr[d], hi = rowptr[d + 1];
    const float4 ad4 = *(const float4*)&a1d[d * 4];

    // ---- phase 1: online softmax stats per head ----
    float mx0 = NEG_BIG, mx1 = NEG_BIG, mx2 = NEG_BIG, mx3 = NEG_BIG;
    float sm0 = 0.f, sm1 = 0.f, sm2 = 0.f, sm3 = 0.f;
    for (int j = lo + lane; j < hi; j += 64) {
        int s = col[j];
        float4 as4 = *(const float4*)&a1s[s * 4];
        float a0 = as4.x + ad4.x, a1 = as4.y + ad4.y, a2 = as4.z + ad4.z, a3 = as4.w + ad4.w;
        a0 = a0 > 0.f ? a0 : NEG_ATT * a0;
        a1 = a1 > 0.f ? a1 : NEG_ATT * a1;
        a2 = a2 > 0.f ? a2 : NEG_ATT * a2;
        a3 = a3 > 0.f ? a3 : NEG_ATT * a3;
        float m;
        m = fmaxf(mx0, a0); sm0 = sm0 * __expf(mx0 - m) + __expf(a0 - m); mx0 = m;
        m = fmaxf(mx1, a1); sm1 = sm1 * __expf(mx1 - m) + __expf(a1 - m); mx1 = m;
        m = fmaxf(mx2, a2); sm2 = sm2 * __expf(mx2 - m) + __expf(a2 - m); mx2 = m;
        m = fmaxf(mx3, a3); sm3 = sm3 * __expf(mx3 - m) + __expf(a3 - m); mx3 = m;
    }
    #pragma unroll
    for (int off = 32; off >= 1; off >>= 1) {
        float mo, so, m;
        mo = __shfl_xor(mx0, off); so = __shfl_xor(sm0, off);
        m = fmaxf(mx0, mo); sm0 = sm0 * __expf(mx0 - m) + so * __expf(mo - m); mx0 = m;
        mo = __shfl_xor(mx1, off); so = __shfl_xor(sm1, off);
        m = fmaxf(mx1, mo); sm1 = sm1 * __expf(mx1 - m) + so * __expf(mo - m); mx1 = m;
        mo = __shfl_xor(mx2, off); so = __shfl_xor(sm2, off);
        m = fmaxf(mx2, mo); sm2 = sm2 * __expf(mx2 - m) + so * __expf(mo - m); mx2 = m;
        mo = __shfl_xor(mx3, off); so = __shfl_xor(sm3, off);
        m = fmaxf(mx3, mo); sm3 = sm3 * __expf(mx3 - m) + so * __expf(mo - m); mx3 = m;
    }
    const float inv0 = 1.f / (sm0 + 1e-16f), inv1 = 1.f / (sm1 + 1e-16f);
    const float inv2 = 1.f / (sm2 + 1e-16f), inv3 = 1.f / (sm3 + 1e-16f);

    // ---- phase 2: chunked alpha precompute + uniform-base bf16x2 gather ----
    const int hh = lane >> 4;                    // head of channels {2l,2l+1}
    float acc0 = 0.f, acc1 = 0.f;
    for (int base = lo; base < hi; base += 64) {
        const int cnt = min(64, hi - base);
        if (lane < cnt) {
            int s = col[base + lane];
            float4 as4 = *(const float4*)&a1s[s * 4];
            float a0 = as4.x + ad4.x, a1 = as4.y + ad4.y, a2 = as4.z + ad4.z, a3 = as4.w + ad4.w;
            a0 = a0 > 0.f ? a0 : NEG_ATT * a0;
            a1 = a1 > 0.f ? a1 : NEG_ATT * a1;
            a2 = a2 > 0.f ? a2 : NEG_ATT * a2;
            a3 = a3 > 0.f ? a3 : NEG_ATT * a3;
            float4 al;
            al.x = __expf(a0 - mx0) * inv0;
            al.y = __expf(a1 - mx1) * inv1;
            al.z = __expf(a2 - mx2) * inv2;
            al.w = __expf(a3 - mx3) * inv3;
            *(float4*)&als[w][lane][0] = al;
            scol[w][lane] = s;
        }
        __builtin_amdgcn_wave_barrier();
        for (int t = 0; t < cnt; ++t) {
            int s = __builtin_amdgcn_readfirstlane(scol[w][t]);   // SGPR row index
            float al = als[w][t][hh];
            const unsigned* row = h1q + (size_t)s * 64;           // SGPR base
            unsigned v = row[lane];                               // const lane*4 voffset
            acc0 = fmaf(bflo(v), al, acc0);
            acc1 = fmaf(bfhi(v), al, acc1);
        }
        __builtin_amdgcn_wave_barrier();
    }
    float2 outv;
    outv.x = acc0 + b1[2 * lane];
    outv.y = acc1 + b1[2 * lane + 1];
    *(float2*)&g1[(long)d * 128 + 2 * lane] = outv;
}

// ============================ GEMM2 fused: h2b = bf16(leaky(g1) @ W2), + a2s/a2d ============================
__global__ void k_gemm2(const float* __restrict__ g1, const float* __restrict__ W2,
                        const float* __restrict__ a2srcv, const float* __restrict__ a2dstv,
                        bf16* __restrict__ h2b, float* __restrict__ a2s, float* __restrict__ a2d,
                        int N) {
    __shared__ float xs[128];
    const int n = blockIdx.x, j = threadIdx.x;   // 64 threads
    for (int t = j; t < 128; t += 64) {
        float v = g1[(long)n * 128 + t];
        xs[t] = v > 0.f ? v : NEG_ACT * v;
    }
    __syncthreads();
    float acc = 0.f;
    for (int k = 0; k < 128; ++k) acc = fmaf(xs[k], W2[k * 64 + j], acc);
    h2b[(long)n * 64 + j] = __float2bfloat16(acc);
    float vs = acc * a2srcv[j], vd = acc * a2dstv[j];
    #pragma unroll
    for (int m = 32; m >= 1; m >>= 1) {
        vs += __shfl_xor(vs, m);
        vd += __shfl_xor(vd, m);
    }
    if (j == 0) { a2s[n] = vs; a2d[n] = vd; }
}

// ============================ layer-2 fused softmax+aggregate ============================
// phase 2: full wave per edge; lane owns channel `lane` (one bf16/ushort, SGPR row base).
// No cross-lane combine needed; direct store.
__global__ void k_aggr2(const int* __restrict__ rowptr, const int* __restrict__ col,
                        const unsigned short* __restrict__ h2s, const float* __restrict__ a2s,
                        const float* __restrict__ a2d, const float* __restrict__ b2,
                        float* __restrict__ zout, int N) {
    __shared__ float als[4][64];
    __shared__ int   scol[4][64];
    const int w = threadIdx.x >> 6;
    const int lane = threadIdx.x & 63;
    const int d = blockIdx.x * 4 + w;
    if (d >= N) return;
    const int lo = rowptr[d], hi = rowptr[d + 1];
    const float ad = a2d[d];

    float mx = NEG_BIG, sm = 0.f;
    for (int j = lo + lane; j < hi; j += 64) {
        int s = col[j];
        float a = a2s[s] + ad;
        a = a > 0.f ? a : NEG_ATT * a;
        float m = fmaxf(mx, a);
        sm = sm * __expf(mx - m) + __expf(a - m);
        mx = m;
    }
    #pragma unroll
    for (int off = 32; off >= 1; off >>= 1) {
        float mo = __shfl_xor(mx, off), so = __shfl_xor(sm, off);
        float m = fmaxf(mx, mo);
        sm = sm * __expf(mx - m) + so * __expf(mo - m);
        mx = m;
    }
    const float inv = 1.f / (sm + 1e-16f);

    float acc = 0.f;
    for (int base = lo; base < hi; base += 64) {
        const int cnt = min(64, hi - base);
        if (lane < cnt) {
            int s = col[base + lane];
            float a = a2s[s] + ad;
            a = a > 0.f ? a : NEG_ATT * a;
            als[w][lane] = __expf(a - mx) * inv;
            scol[w][lane] = s;
        }
        __builtin_amdgcn_wave_barrier();
        for (int t = 0; t < cnt; ++t) {
            int s = __builtin_amdgcn_readfirstlane(scol[w][t]);   // SGPR row index
            float al = als[w][t];
            const unsigned short* row = h2s + (size_t)s * 64;     // SGPR base
            float v = __uint_as_float((unsigned)row[lane] << 16); // const lane*2 voffset
            acc = fmaf(v, al, acc);
        }
        __builtin_amdgcn_wave_barrier();
    }
    zout[(long)d * 64 + lane] = acc + b2[lane];
}

// ============================ decoder node-level precompute (bf16 out) ============================
__global__ void k_uv(const float* __restrict__ z, const float* __restrict__ Wd1,
                     const float* __restrict__ bd1,
                     bf16* __restrict__ u, bf16* __restrict__ v, int N) {
    __shared__ float zs[4][64];
    const int w = threadIdx.x >> 6;              // node slot 0..3
    const int lane = threadIdx.x & 63;
    const int n = blockIdx.x * 4 + w;
    if (n < N) zs[w][lane] = z[(long)n * 64 + lane];
    __syncthreads();
    if (n >= N) return;
    const int jj = lane & 31;
    const int base = (lane < 32) ? 0 : 64 * 32;  // top half -> u, bottom -> v
    float acc = (lane < 32) ? bd1[jj] : 0.f;
    #pragma unroll
    for (int k = 0; k < 64; ++k)
        acc = fmaf(zs[w][k], Wd1[base + k * 32 + jj], acc);
    if (lane < 32) u[(long)n * 32 + jj] = __float2bfloat16(acc);
    else           v[(long)n * 32 + jj] = __float2bfloat16(acc);
}

// ============================ decoder per-edge: relu(u[s]+v[d]) . Wd2 + bd2 ============================
__global__ void k_dec2(const int* __restrict__ ei, int E,
                       const bf16* __restrict__ u, const bf16* __restrict__ v,
                       const float* __restrict__ Wd2, const float* __restrict__ bd2,
                       float* __restrict__ pred) {
    const int g = threadIdx.x >> 3;      // edge slot 0..31
    const int l = threadIdx.x & 7;       // lane in group
    long e = (long)blockIdx.x * 32 + g;
    if (e >= E) return;
    int s = ei[e], d = ei[E + e];
    uint2 ua = *(const uint2*)(u + (long)s * 32 + l * 4);
    uint2 vb = *(const uint2*)(v + (long)d * 32 + l * 4);
    float4 wv = *(const float4*)&Wd2[l * 4];
    float h0 = fmaxf(bflo(ua.x) + bflo(vb.x), 0.f);
    float h1 = fmaxf(bfhi(ua.x) + bfhi(vb.x), 0.f);
    float h2 = fmaxf(bflo(ua.y) + bflo(vb.y), 0.f);
    float h3 = fmaxf(bfhi(ua.y) + bfhi(vb.y), 0.f);
    float p = h0 * wv.x;
    p = fmaf(h1, wv.y, p);
    p = fmaf(h2, wv.z, p);
    p = fmaf(h3, wv.w, p);
    p += __shfl_xor(p, 1, 8);
    p += __shfl_xor(p, 2, 8);
    p += __shfl_xor(p, 4, 8);
    if (l == 0) pred[e] = p + bd2[0];
}

// ============================ launch ============================
extern "C" void kernel_launch(void* const* d_in, const int* in_sizes, int n_in,
                              void* d_out, int out_size, void* d_ws, size_t ws_size,
                              hipStream_t stream) {
    const float* x    = (const float*)d_in[0];
    const int*   ei   = (const int*)d_in[1];
    const float* W1   = (const float*)d_in[2];
    const float* a1sw = (const float*)d_in[3];
    const float* a1dw = (const float*)d_in[4];
    const float* b1   = (const float*)d_in[5];
    const float* W2   = (const float*)d_in[6];
    const float* a2sw = (const float*)d_in[7];
    const float* a2dw = (const float*)d_in[8];
    const float* b2   = (const float*)d_in[9];
    const float* Wd1  = (const float*)d_in[10];
    const float* bd1  = (const float*)d_in[11];
    const float* Wd2  = (const float*)d_in[12];
    const float* bd2  = (const float*)d_in[13];

    const int N = in_sizes[0] / 128;        // 50000
    const int E = in_sizes[1] / 2;          // 1600000
    const int E2 = E + N;

    float* pred = (float*)d_out;            // [E]
    float* zout = (float*)d_out + E;        // [N,64]

    // workspace layout (float-slot units)
    float* W = (float*)d_ws;
    size_t o = 0;
    float* g1  = W + o; o += (size_t)N * 128;
    bf16* h1b  = (bf16*)(W + o); o += (size_t)N * 64;   // N*128 bf16
    bf16* h2b  = (bf16*)(W + o); o += (size_t)N * 32;   // N*64 bf16
    bf16* ub   = (bf16*)(W + o); o += (size_t)N * 16;   // N*32 bf16
    bf16* vb   = (bf16*)(W + o); o += (size_t)N * 16;   // N*32 bf16
    float* a1s = W + o; o += (size_t)N * 4;
    float* a1d = W + o; o += (size_t)N * 4;
    float* a2s = W + o; o += (size_t)N;
    float* a2d = W + o; o += (size_t)N;
    int* counts = (int*)(W + o); o += (size_t)N;
    int* rowptr = (int*)(W + o); o += (size_t)N + 1;
    int* cursor = (int*)(W + o); o += (size_t)N;
    int* col    = (int*)(W + o); o += (size_t)E2;
    int* bsum   = (int*)(W + o); o += 256;
    if (ws_size < o * sizeof(float)) return;

    const int TB = 256;
    const int gE = (E2 + TB - 1) / TB;
    const int NB = (N + 255) / 256;

    // CSR build
    k_zero<<<(N + TB - 1) / TB, TB, 0, stream>>>(counts, N);
    k_count<<<gE * NRANGE, TB, 0, stream>>>(ei, E, N, counts);
    k_scan1<<<NB, 256, 0, stream>>>(counts, N, bsum);
    k_scan2<<<1, 256, 0, stream>>>(bsum, NB, &rowptr[N]);
    k_scan3<<<NB, 256, 0, stream>>>(counts, N, bsum, rowptr, cursor);
    k_scatter<<<gE * NRANGE, TB, 0, stream>>>(ei, E, N, cursor, col);

    // layer 1 (att1 fused into gemm1)
    k_gemm1<<<(N + 7) / 8, 128, 0, stream>>>(x, W1, a1sw, a1dw, h1b, a1s, a1d, N);
    k_aggr1<<<(N + 3) / 4, 256, 0, stream>>>(rowptr, col, (const unsigned*)h1b, a1s, a1d, b1, g1, N);

    // layer 2
    k_gemm2<<<N, 64, 0, stream>>>(g1, W2, a2sw, a2dw, h2b, a2s, a2d, N);
    k_aggr2<<<(N + 3) / 4, 256, 0, stream>>>(rowptr, col, (const unsigned short*)h2b, a2s, a2d, b2, zout, N);

    // decoder
    k_uv<<<(N + 3) / 4, 256, 0, stream>>>(zout, Wd1, bd1, ub, vb, N);
    k_dec2<<<(E + 31) / 32, TB, 0, stream>>>(ei, E, ub, vb, Wd2, bd2, pred);
}

// Round 10
// 424.292 us; speedup vs baseline: 1.2447x; 1.2447x over previous
//
#include <hip/hip_runtime.h>
#include <hip/hip_bf16.h>
#include <math.h>

#define NEG_ATT 0.2f
#define NEG_ACT 0.01f
#define NEG_BIG -1e30f
#define NRANGE 8   // dst-space ranges, mapped to XCDs via blockIdx%8

typedef __hip_bfloat16  bf16;

__device__ __forceinline__ float bflo(unsigned w) { return __uint_as_float(w << 16); }
__device__ __forceinline__ float bfhi(unsigned w) { return __uint_as_float(w & 0xFFFF0000u); }

// ============================ CSR build ============================
__global__ void k_zero(int* __restrict__ counts, int N) {
    int i = blockIdx.x * blockDim.x + threadIdx.x;
    if (i < N) counts[i] = 0;
}

__global__ void k_count(const int* __restrict__ ei, int E, int N, int* __restrict__ counts) {
    const int r = blockIdx.x & (NRANGE - 1);
    const int e = (blockIdx.x >> 3) * blockDim.x + threadIdx.x;
    if (e >= E + N) return;
    const int dlo = (int)(((long)r * N) / NRANGE);
    const int dhi = (int)(((long)(r + 1) * N) / NRANGE);
    int d = (e < E) ? ei[E + e] : e - E;
    if (d < dlo || d >= dhi) return;
    atomicAdd(&counts[d], 1);
}

__global__ void k_scan1(const int* __restrict__ counts, int N, int* __restrict__ bsum) {
    const int i = blockIdx.x * 256 + threadIdx.x;
    int v = (i < N) ? counts[i] : 0;
    #pragma unroll
    for (int off = 32; off >= 1; off >>= 1) v += __shfl_xor(v, off);
    __shared__ int ws[4];
    if ((threadIdx.x & 63) == 0) ws[threadIdx.x >> 6] = v;
    __syncthreads();
    if (threadIdx.x == 0) bsum[blockIdx.x] = ws[0] + ws[1] + ws[2] + ws[3];
}

__global__ void k_scan2(int* __restrict__ bsum, int NB, int* __restrict__ rowptrN) {
    __shared__ int ps[256];
    const int t = threadIdx.x;
    int v = (t < NB) ? bsum[t] : 0;
    ps[t] = v;
    __syncthreads();
    for (int off = 1; off < 256; off <<= 1) {
        int u = (t >= off) ? ps[t - off] : 0;
        __syncthreads();
        ps[t] += u;
        __syncthreads();
    }
    if (t < NB) bsum[t] = ps[t] - v;          // exclusive
    if (t == 255) *rowptrN = ps[255];         // total
}

__global__ void k_scan3(const int* __restrict__ counts, int N, const int* __restrict__ bsum,
                        int* __restrict__ rowptr, int* __restrict__ cursor) {
    __shared__ int ps[256];
    const int t = threadIdx.x;
    const int i = blockIdx.x * 256 + t;
    int v = (i < N) ? counts[i] : 0;
    ps[t] = v;
    __syncthreads();
    for (int off = 1; off < 256; off <<= 1) {
        int u = (t >= off) ? ps[t - off] : 0;
        __syncthreads();
        ps[t] += u;
        __syncthreads();
    }
    if (i < N) {
        int ex = ps[t] - v + bsum[blockIdx.x];
        rowptr[i] = ex;
        cursor[i] = ex;
    }
}

__global__ void k_scatter(const int* __restrict__ ei, int E, int N,
                          int* __restrict__ cursor, int* __restrict__ col) {
    const int r = blockIdx.x & (NRANGE - 1);
    const int e = (blockIdx.x >> 3) * blockDim.x + threadIdx.x;
    if (e >= E + N) return;
    const int dlo = (int)(((long)r * N) / NRANGE);
    const int dhi = (int)(((long)(r + 1) * N) / NRANGE);
    int d = (e < E) ? ei[E + e] : e - E;
    if (d < dlo || d >= dhi) return;
    int s = (e < E) ? ei[e] : d;
    int pos = atomicAdd(&cursor[d], 1);
    col[pos] = s;
}

// ============================ GEMM1 fused with att1: h1b = bf16(x@W1), a1s/a1d ============================
__global__ void k_gemm1(const float* __restrict__ x, const float* __restrict__ W1,
                        const float* __restrict__ a1sw, const float* __restrict__ a1dw,
                        bf16* __restrict__ h1b, float* __restrict__ a1s, float* __restrict__ a1d,
                        int N) {
    __shared__ float xs[8][128];
    const int j = threadIdx.x;
    const int row0 = blockIdx.x * 8;
    #pragma unroll
    for (int r = 0; r < 8; ++r) {
        int n = row0 + r;
        xs[r][j] = (n < N) ? x[(long)n * 128 + j] : 0.f;
    }
    __syncthreads();
    float acc[8];
    #pragma unroll
    for (int r = 0; r < 8; ++r) acc[r] = 0.f;
    for (int k = 0; k < 128; ++k) {
        float w = W1[k * 128 + j];
        #pragma unroll
        for (int r = 0; r < 8; ++r) acc[r] = fmaf(xs[r][k], w, acc[r]);
    }
    const float asw = a1sw[j], adw = a1dw[j];
    #pragma unroll
    for (int r = 0; r < 8; ++r) {
        int n = row0 + r;
        float vs = acc[r] * asw, vd = acc[r] * adw;
        #pragma unroll
        for (int m = 16; m >= 1; m >>= 1) {
            vs += __shfl_xor(vs, m, 32);
            vd += __shfl_xor(vd, m, 32);
        }
        if (n < N) {
            h1b[(long)n * 128 + j] = __float2bfloat16(acc[r]);
            if ((j & 31) == 0) { a1s[n * 4 + (j >> 5)] = vs; a1d[n * 4 + (j >> 5)] = vd; }
        }
    }
}

// ============================ layer-1 fused softmax+aggregate (deferred normalization) ============================
// phase 1: max only. phase 2: per-chunk alpha=exp(a-m) in LDS (+ per-lane weight sums),
// full-wave-per-edge bf16x2 gather with per-lane vector addressing (measured-best form).
// Final: wave-reduce weight sums, divide accumulators.
__global__ void k_aggr1(const int* __restrict__ rowptr, const int* __restrict__ col,
                        const unsigned* __restrict__ h1q, const float* __restrict__ a1s,
                        const float* __restrict__ a1d, const float* __restrict__ b1,
                        float* __restrict__ g1, int N) {
    __shared__ float als[4][64][4];
    __shared__ int   scol[4][64];
    const int w = threadIdx.x >> 6;
    const int lane = threadIdx.x & 63;
    const int d = blockIdx.x * 4 + w;
    if (d >= N) return;
    const int lo = rowptr[d], hi = rowptr[d + 1];
    const float4 ad4 = *(const float4*)&a1d[d * 4];

    // ---- phase 1: per-head max only ----
    float mx0 = NEG_BIG, mx1 = NEG_BIG, mx2 = NEG_BIG, mx3 = NEG_BIG;
    for (int j = lo + lane; j < hi; j += 64) {
        int s = col[j];
        float4 as4 = *(const float4*)&a1s[s * 4];
        float a0 = as4.x + ad4.x, a1 = as4.y + ad4.y, a2 = as4.z + ad4.z, a3 = as4.w + ad4.w;
        a0 = a0 > 0.f ? a0 : NEG_ATT * a0;
        a1 = a1 > 0.f ? a1 : NEG_ATT * a1;
        a2 = a2 > 0.f ? a2 : NEG_ATT * a2;
        a3 = a3 > 0.f ? a3 : NEG_ATT * a3;
        mx0 = fmaxf(mx0, a0); mx1 = fmaxf(mx1, a1);
        mx2 = fmaxf(mx2, a2); mx3 = fmaxf(mx3, a3);
    }
    #pragma unroll
    for (int off = 32; off >= 1; off >>= 1) {
        mx0 = fmaxf(mx0, __shfl_xor(mx0, off));
        mx1 = fmaxf(mx1, __shfl_xor(mx1, off));
        mx2 = fmaxf(mx2, __shfl_xor(mx2, off));
        mx3 = fmaxf(mx3, __shfl_xor(mx3, off));
    }

    // ---- phase 2: chunked unnormalized weights + gather ----
    const int hh = lane >> 4;                    // head of channels {2l,2l+1}
    float acc0 = 0.f, acc1 = 0.f;
    float ws0 = 0.f, ws1 = 0.f, ws2 = 0.f, ws3 = 0.f;
    for (int base = lo; base < hi; base += 64) {
        const int cnt = min(64, hi - base);
        if (lane < cnt) {
            int s = col[base + lane];
            float4 as4 = *(const float4*)&a1s[s * 4];
            float a0 = as4.x + ad4.x, a1 = as4.y + ad4.y, a2 = as4.z + ad4.z, a3 = as4.w + ad4.w;
            a0 = a0 > 0.f ? a0 : NEG_ATT * a0;
            a1 = a1 > 0.f ? a1 : NEG_ATT * a1;
            a2 = a2 > 0.f ? a2 : NEG_ATT * a2;
            a3 = a3 > 0.f ? a3 : NEG_ATT * a3;
            float4 al;
            al.x = __expf(a0 - mx0);
            al.y = __expf(a1 - mx1);
            al.z = __expf(a2 - mx2);
            al.w = __expf(a3 - mx3);
            ws0 += al.x; ws1 += al.y; ws2 += al.z; ws3 += al.w;
            *(float4*)&als[w][lane][0] = al;
            scol[w][lane] = s;
        }
        __builtin_amdgcn_wave_barrier();
        for (int t = 0; t < cnt; ++t) {
            int s = scol[w][t];
            float al = als[w][t][hh];
            unsigned v = h1q[(size_t)s * 64 + lane];
            acc0 = fmaf(bflo(v), al, acc0);
            acc1 = fmaf(bfhi(v), al, acc1);
        }
        __builtin_amdgcn_wave_barrier();
    }
    // ---- reduce weight sums, normalize ----
    #pragma unroll
    for (int off = 32; off >= 1; off >>= 1) {
        ws0 += __shfl_xor(ws0, off);
        ws1 += __shfl_xor(ws1, off);
        ws2 += __shfl_xor(ws2, off);
        ws3 += __shfl_xor(ws3, off);
    }
    float wsel = (hh == 0) ? ws0 : (hh == 1) ? ws1 : (hh == 2) ? ws2 : ws3;
    float inv = 1.f / (wsel + 1e-16f);
    float2 outv;
    outv.x = acc0 * inv + b1[2 * lane];
    outv.y = acc1 * inv + b1[2 * lane + 1];
    *(float2*)&g1[(long)d * 128 + 2 * lane] = outv;
}

// ============================ GEMM2 fused: h2b = bf16(leaky(g1) @ W2), + a2s/a2d ============================
__global__ void k_gemm2(const float* __restrict__ g1, const float* __restrict__ W2,
                        const float* __restrict__ a2srcv, const float* __restrict__ a2dstv,
                        bf16* __restrict__ h2b, float* __restrict__ a2s, float* __restrict__ a2d,
                        int N) {
    __shared__ float xs[128];
    const int n = blockIdx.x, j = threadIdx.x;   // 64 threads
    for (int t = j; t < 128; t += 64) {
        float v = g1[(long)n * 128 + t];
        xs[t] = v > 0.f ? v : NEG_ACT * v;
    }
    __syncthreads();
    float acc = 0.f;
    for (int k = 0; k < 128; ++k) acc = fmaf(xs[k], W2[k * 64 + j], acc);
    h2b[(long)n * 64 + j] = __float2bfloat16(acc);
    float vs = acc * a2srcv[j], vd = acc * a2dstv[j];
    #pragma unroll
    for (int m = 32; m >= 1; m >>= 1) {
        vs += __shfl_xor(vs, m);
        vd += __shfl_xor(vd, m);
    }
    if (j == 0) { a2s[n] = vs; a2d[n] = vd; }
}

// ============================ layer-2 fused softmax+aggregate (deferred normalization) ============================
// full wave per edge; lane owns channel `lane` (ushort load, per-lane vector addressing).
__global__ void k_aggr2(const int* __restrict__ rowptr, const int* __restrict__ col,
                        const unsigned short* __restrict__ h2s, const float* __restrict__ a2s,
                        const float* __restrict__ a2d, const float* __restrict__ b2,
                        float* __restrict__ zout, int N) {
    __shared__ float als[4][64];
    __shared__ int   scol[4][64];
    const int w = threadIdx.x >> 6;
    const int lane = threadIdx.x & 63;
    const int d = blockIdx.x * 4 + w;
    if (d >= N) return;
    const int lo = rowptr[d], hi = rowptr[d + 1];
    const float ad = a2d[d];

    // ---- phase 1: max only ----
    float mx = NEG_BIG;
    for (int j = lo + lane; j < hi; j += 64) {
        int s = col[j];
        float a = a2s[s] + ad;
        a = a > 0.f ? a : NEG_ATT * a;
        mx = fmaxf(mx, a);
    }
    #pragma unroll
    for (int off = 32; off >= 1; off >>= 1) mx = fmaxf(mx, __shfl_xor(mx, off));

    // ---- phase 2 ----
    float acc = 0.f, wsum = 0.f;
    for (int base = lo; base < hi; base += 64) {
        const int cnt = min(64, hi - base);
        if (lane < cnt) {
            int s = col[base + lane];
            float a = a2s[s] + ad;
            a = a > 0.f ? a : NEG_ATT * a;
            float al = __expf(a - mx);
            wsum += al;
            als[w][lane] = al;
            scol[w][lane] = s;
        }
        __builtin_amdgcn_wave_barrier();
        for (int t = 0; t < cnt; ++t) {
            int s = scol[w][t];
            float al = als[w][t];
            float v = __uint_as_float((unsigned)h2s[(size_t)s * 64 + lane] << 16);
            acc = fmaf(v, al, acc);
        }
        __builtin_amdgcn_wave_barrier();
    }
    #pragma unroll
    for (int off = 32; off >= 1; off >>= 1) wsum += __shfl_xor(wsum, off);
    zout[(long)d * 64 + lane] = acc / (wsum + 1e-16f) + b2[lane];
}

// ============================ decoder node-level precompute (bf16 out) ============================
__global__ void k_uv(const float* __restrict__ z, const float* __restrict__ Wd1,
                     const float* __restrict__ bd1,
                     bf16* __restrict__ u, bf16* __restrict__ v, int N) {
    __shared__ float zs[4][64];
    const int w = threadIdx.x >> 6;              // node slot 0..3
    const int lane = threadIdx.x & 63;
    const int n = blockIdx.x * 4 + w;
    if (n < N) zs[w][lane] = z[(long)n * 64 + lane];
    __syncthreads();
    if (n >= N) return;
    const int jj = lane & 31;
    const int base = (lane < 32) ? 0 : 64 * 32;  // top half -> u, bottom -> v
    float acc = (lane < 32) ? bd1[jj] : 0.f;
    #pragma unroll
    for (int k = 0; k < 64; ++k)
        acc = fmaf(zs[w][k], Wd1[base + k * 32 + jj], acc);
    if (lane < 32) u[(long)n * 32 + jj] = __float2bfloat16(acc);
    else           v[(long)n * 32 + jj] = __float2bfloat16(acc);
}

// ============================ decoder per-edge: relu(u[s]+v[d]) . Wd2 + bd2 ============================
__global__ void k_dec2(const int* __restrict__ ei, int E,
                       const bf16* __restrict__ u, const bf16* __restrict__ v,
                       const float* __restrict__ Wd2, const float* __restrict__ bd2,
                       float* __restrict__ pred) {
    const int g = threadIdx.x >> 3;      // edge slot 0..31
    const int l = threadIdx.x & 7;       // lane in group
    long e = (long)blockIdx.x * 32 + g;
    if (e >= E) return;
    int s = ei[e], d = ei[E + e];
    uint2 ua = *(const uint2*)(u + (long)s * 32 + l * 4);
    uint2 vb = *(const uint2*)(v + (long)d * 32 + l * 4);
    float4 wv = *(const float4*)&Wd2[l * 4];
    float h0 = fmaxf(bflo(ua.x) + bflo(vb.x), 0.f);
    float h1 = fmaxf(bfhi(ua.x) + bfhi(vb.x), 0.f);
    float h2 = fmaxf(bflo(ua.y) + bflo(vb.y), 0.f);
    float h3 = fmaxf(bfhi(ua.y) + bfhi(vb.y), 0.f);
    float p = h0 * wv.x;
    p = fmaf(h1, wv.y, p);
    p = fmaf(h2, wv.z, p);
    p = fmaf(h3, wv.w, p);
    p += __shfl_xor(p, 1, 8);
    p += __shfl_xor(p, 2, 8);
    p += __shfl_xor(p, 4, 8);
    if (l == 0) pred[e] = p + bd2[0];
}

// ============================ launch ============================
extern "C" void kernel_launch(void* const* d_in, const int* in_sizes, int n_in,
                              void* d_out, int out_size, void* d_ws, size_t ws_size,
                              hipStream_t stream) {
    const float* x    = (const float*)d_in[0];
    const int*   ei   = (const int*)d_in[1];
    const float* W1   = (const float*)d_in[2];
    const float* a1sw = (const float*)d_in[3];
    const float* a1dw = (const float*)d_in[4];
    const float* b1   = (const float*)d_in[5];
    const float* W2   = (const float*)d_in[6];
    const float* a2sw = (const float*)d_in[7];
    const float* a2dw = (const float*)d_in[8];
    const float* b2   = (const float*)d_in[9];
    const float* Wd1  = (const float*)d_in[10];
    const float* bd1  = (const float*)d_in[11];
    const float* Wd2  = (const float*)d_in[12];
    const float* bd2  = (const float*)d_in[13];

    const int N = in_sizes[0] / 128;        // 50000
    const int E = in_sizes[1] / 2;          // 1600000
    const int E2 = E + N;

    float* pred = (float*)d_out;            // [E]
    float* zout = (float*)d_out + E;        // [N,64]

    // workspace layout (float-slot units)
    float* W = (float*)d_ws;
    size_t o = 0;
    float* g1  = W + o; o += (size_t)N * 128;
    bf16* h1b  = (bf16*)(W + o); o += (size_t)N * 64;   // N*128 bf16
    bf16* h2b  = (bf16*)(W + o); o += (size_t)N * 32;   // N*64 bf16
    bf16* ub   = (bf16*)(W + o); o += (size_t)N * 16;   // N*32 bf16
    bf16* vb   = (bf16*)(W + o); o += (size_t)N * 16;   // N*32 bf16
    float* a1s = W + o; o += (size_t)N * 4;
    float* a1d = W + o; o += (size_t)N * 4;
    float* a2s = W + o; o += (size_t)N;
    float* a2d = W + o; o += (size_t)N;
    int* counts = (int*)(W + o); o += (size_t)N;
    int* rowptr = (int*)(W + o); o += (size_t)N + 1;
    int* cursor = (int*)(W + o); o += (size_t)N;
    int* col    = (int*)(W + o); o += (size_t)E2;
    int* bsum   = (int*)(W + o); o += 256;
    if (ws_size < o * sizeof(float)) return;

    const int TB = 256;
    const int gE = (E2 + TB - 1) / TB;
    const int NB = (N + 255) / 256;

    // CSR build
    k_zero<<<(N + TB - 1) / TB, TB, 0, stream>>>(counts, N);
    k_count<<<gE * NRANGE, TB, 0, stream>>>(ei, E, N, counts);
    k_scan1<<<NB, 256, 0, stream>>>(counts, N, bsum);
    k_scan2<<<1, 256, 0, stream>>>(bsum, NB, &rowptr[N]);
    k_scan3<<<NB, 256, 0, stream>>>(counts, N, bsum, rowptr, cursor);
    k_scatter<<<gE * NRANGE, TB, 0, stream>>>(ei, E, N, cursor, col);

    // layer 1 (att1 fused into gemm1)
    k_gemm1<<<(N + 7) / 8, 128, 0, stream>>>(x, W1, a1sw, a1dw, h1b, a1s, a1d, N);
    k_aggr1<<<(N + 3) / 4, 256, 0, stream>>>(rowptr, col, (const unsigned*)h1b, a1s, a1d, b1, g1, N);

    // layer 2
    k_gemm2<<<N, 64, 0, stream>>>(g1, W2, a2sw, a2dw, h2b, a2s, a2d, N);
    k_aggr2<<<(N + 3) / 4, 256, 0, stream>>>(rowptr, col, (const unsigned short*)h2b, a2s, a2d, b2, zout, N);

    // decoder
    k_uv<<<(N + 3) / 4, 256, 0, stream>>>(zout, Wd1, bd1, ub, vb, N);
    k_dec2<<<(E + 31) / 32, TB, 0, stream>>>(ei, E, ub, vb, Wd2, bd2, pred);
}